// Round 2
// baseline (3772.001 us; speedup 1.0000x reference)
//
#include <hip/hip_runtime.h>
#include <stdint.h>

// Predictive-coding inference: LAYER_SZS=[1024,4096,4096,4096,1024], B=2048, 5 iters.
// All GEMMs: C[M,N] = A[M,K](bf16) @ W[N,K](bf16)^T, f32 accum, bf16 or f32 out.
// State kept in bf16 to fit d_ws; adaptive layout (fast: weights pre-converted;
// slim: rotating weight stage) chosen by ws_size.

typedef __attribute__((ext_vector_type(8))) __bf16 bf16x8;
typedef __attribute__((ext_vector_type(4))) float f32x4;

#define B_ 2048

__device__ __forceinline__ unsigned short f2bf(float f) {
  union { float f; unsigned u; } v; v.f = f;
  unsigned u = v.u;
  u += 0x7FFFu + ((u >> 16) & 1u);
  return (unsigned short)(u >> 16);
}
__device__ __forceinline__ float bf2f(unsigned short s) {
  union { unsigned u; float f; } v; v.u = ((unsigned)s) << 16;
  return v.f;
}
__device__ __forceinline__ float fast_sig(float x) {
  return 1.0f / (1.0f + __expf(-x));
}
__device__ __forceinline__ float fast_tanh(float x) {
  return 1.0f - 2.0f / (__expf(2.0f * x) + 1.0f);
}

__device__ __forceinline__ void gload_lds16(const void* g, void* l) {
  __builtin_amdgcn_global_load_lds((const __attribute__((address_space(1))) void*)g,
                                   (__attribute__((address_space(3))) void*)l, 16, 0, 0);
}

// ---------------- GEMM: C[M,N] = A(bf16)[M,K] * W(bf16)[N,K]^T -------------
template <typename OutT>
__global__ __launch_bounds__(256) void gemm_bt(
    const unsigned short* __restrict__ A,
    const unsigned short* __restrict__ W,
    OutT* __restrict__ C,
    int M, int N, int K)
{
  __shared__ alignas(16) unsigned short As[128 * 64];
  __shared__ alignas(16) unsigned short Bs[128 * 64];
  const int tid  = threadIdx.x;
  const int wave = tid >> 6, lane = tid & 63;
  const int wrow = wave >> 1, wcol = wave & 1;
  const int row0 = blockIdx.y << 7, col0 = blockIdx.x << 7;

  f32x4 acc[4][4];
#pragma unroll
  for (int m = 0; m < 4; ++m)
#pragma unroll
    for (int n = 0; n < 4; ++n) acc[m][n] = (f32x4){0.f, 0.f, 0.f, 0.f};

  const int lr = lane >> 3;          // row within 8-row group
  const int lc = (lane & 7) * 8;     // col (shorts; 16B chunk)
  const int nk = K >> 6;             // BK = 64

  for (int kt = 0; kt < nk; ++kt) {
    const int k0 = kt << 6;
#pragma unroll
    for (int i = 0; i < 4; ++i) {
      const int rbase = i * 32 + wave * 8;   // wave-uniform
      gload_lds16(A + (size_t)(row0 + rbase + lr) * K + k0 + lc, As + rbase * 64);
      gload_lds16(W + (size_t)(col0 + rbase + lr) * K + k0 + lc, Bs + rbase * 64);
    }
    __syncthreads();
#pragma unroll
    for (int kk = 0; kk < 2; ++kk) {
      const int ko = kk * 32 + (lane >> 4) * 8;
      bf16x8 av[4], bv[4];
#pragma unroll
      for (int m = 0; m < 4; ++m)
        av[m] = *(const bf16x8*)(As + (wrow * 64 + m * 16 + (lane & 15)) * 64 + ko);
#pragma unroll
      for (int n = 0; n < 4; ++n)
        bv[n] = *(const bf16x8*)(Bs + (wcol * 64 + n * 16 + (lane & 15)) * 64 + ko);
#pragma unroll
      for (int m = 0; m < 4; ++m)
#pragma unroll
        for (int n = 0; n < 4; ++n)
          acc[m][n] = __builtin_amdgcn_mfma_f32_16x16x32_bf16(av[m], bv[n], acc[m][n], 0, 0, 0);
    }
    __syncthreads();
  }

  // epilogue: D row = (lane>>4)*4 + j, col = lane&15  (m89-verified layout)
#pragma unroll
  for (int m = 0; m < 4; ++m) {
#pragma unroll
    for (int n = 0; n < 4; ++n) {
      const int r = row0 + wrow * 64 + m * 16 + ((lane >> 4) << 2);
      const int c = col0 + wcol * 64 + n * 16 + (lane & 15);
#pragma unroll
      for (int j = 0; j < 4; ++j) {
        if constexpr (sizeof(OutT) == 4)
          C[(size_t)(r + j) * N + c] = acc[m][n][j];
        else
          C[(size_t)(r + j) * N + c] = f2bf(acc[m][n][j]);
      }
    }
  }
}

// ---------------- elementwise kernels (vectorized, grid-stride) ----------
__global__ void k_cvt(const float* __restrict__ in, unsigned short* __restrict__ out, int n4) {
  int i = blockIdx.x * blockDim.x + threadIdx.x, st = gridDim.x * blockDim.x;
  for (; i < n4; i += st) {
    float4 v = ((const float4*)in)[i];
    ushort4 o; o.x = f2bf(v.x); o.y = f2bf(v.y); o.z = f2bf(v.z); o.w = f2bf(v.w);
    ((ushort4*)out)[i] = o;
  }
}

// t = bf16(tanh(p)); a = relu(t) (bit-exact relu of the bf16 tanh)
__global__ void k_tanh_relu(const unsigned short* __restrict__ p,
                            unsigned short* __restrict__ t,
                            unsigned short* __restrict__ a, int n4) {
  int i = blockIdx.x * blockDim.x + threadIdx.x, st = gridDim.x * blockDim.x;
  for (; i < n4; i += st) {
    ushort4 pv = ((const ushort4*)p)[i];
    ushort4 tv, av;
    tv.x = f2bf(fast_tanh(bf2f(pv.x))); av.x = (tv.x & 0x8000u) ? 0 : tv.x;
    tv.y = f2bf(fast_tanh(bf2f(pv.y))); av.y = (tv.y & 0x8000u) ? 0 : tv.y;
    tv.z = f2bf(fast_tanh(bf2f(pv.z))); av.z = (tv.z & 0x8000u) ? 0 : tv.z;
    tv.w = f2bf(fast_tanh(bf2f(pv.w))); av.w = (tv.w & 0x8000u) ? 0 : tv.w;
    ((ushort4*)t)[i] = tv;
    ((ushort4*)a)[i] = av;
  }
}

// a = bf16(relu(tanh(p)))
__global__ void k_act(const unsigned short* __restrict__ p,
                      unsigned short* __restrict__ a, int n4) {
  int i = blockIdx.x * blockDim.x + threadIdx.x, st = gridDim.x * blockDim.x;
  for (; i < n4; i += st) {
    ushort4 pv = ((const ushort4*)p)[i];
    ushort4 av;
    av.x = f2bf(fmaxf(fast_tanh(bf2f(pv.x)), 0.f));
    av.y = f2bf(fmaxf(fast_tanh(bf2f(pv.y)), 0.f));
    av.z = f2bf(fmaxf(fast_tanh(bf2f(pv.z)), 0.f));
    av.w = f2bf(fmaxf(fast_tanh(bf2f(pv.w)), 0.f));
    ((ushort4*)a)[i] = av;
  }
}

// d = bf16((anext - tanh(p)) * (1 - tanh(p)^2))
__global__ void k_delta_tanh(const unsigned short* __restrict__ p,
                             const unsigned short* __restrict__ anext,
                             unsigned short* __restrict__ d, int n4) {
  int i = blockIdx.x * blockDim.x + threadIdx.x, st = gridDim.x * blockDim.x;
  for (; i < n4; i += st) {
    ushort4 pv = ((const ushort4*)p)[i];
    ushort4 av = ((const ushort4*)anext)[i];
    ushort4 o; float t;
    t = fast_tanh(bf2f(pv.x)); o.x = f2bf((bf2f(av.x) - t) * (1.f - t * t));
    t = fast_tanh(bf2f(pv.y)); o.y = f2bf((bf2f(av.y) - t) * (1.f - t * t));
    t = fast_tanh(bf2f(pv.z)); o.z = f2bf((bf2f(av.z) - t) * (1.f - t * t));
    t = fast_tanh(bf2f(pv.w)); o.w = f2bf((bf2f(av.w) - t) * (1.f - t * t));
    ((ushort4*)d)[i] = o;
  }
}

// d = bf16((targ - sig(p3)) * sig'(p3)); p3,targ f32
__global__ void k_delta_sig(const float* __restrict__ p, const float* __restrict__ targ,
                            unsigned short* __restrict__ d, int n4) {
  int i = blockIdx.x * blockDim.x + threadIdx.x, st = gridDim.x * blockDim.x;
  for (; i < n4; i += st) {
    float4 pv = ((const float4*)p)[i];
    float4 tv = ((const float4*)targ)[i];
    ushort4 o; float s;
    s = fast_sig(pv.x); o.x = f2bf((tv.x - s) * s * (1.f - s));
    s = fast_sig(pv.y); o.y = f2bf((tv.y - s) * s * (1.f - s));
    s = fast_sig(pv.z); o.z = f2bf((tv.z - s) * s * (1.f - s));
    s = fast_sig(pv.w); o.w = f2bf((tv.w - s) * s * (1.f - s));
    ((ushort4*)d)[i] = o;
  }
}

// a = bf16(relu(a + 0.1*bt - 0.1*(a - tprev)));  tprev = prev (pre-tanh'd) or tanh(prev)
template <bool APPLY_TANH>
__global__ void k_update(unsigned short* __restrict__ a,
                         const unsigned short* __restrict__ bt,
                         const unsigned short* __restrict__ prev, int n4) {
  int i = blockIdx.x * blockDim.x + threadIdx.x, st = gridDim.x * blockDim.x;
  for (; i < n4; i += st) {
    ushort4 av = ((const ushort4*)a)[i];
    ushort4 bv = ((const ushort4*)bt)[i];
    ushort4 pv = ((const ushort4*)prev)[i];
    ushort4 o;
    {
      float af = bf2f(av.x), tf = APPLY_TANH ? fast_tanh(bf2f(pv.x)) : bf2f(pv.x);
      o.x = f2bf(fmaxf(af + 0.1f * bf2f(bv.x) - 0.1f * (af - tf), 0.f));
    }
    {
      float af = bf2f(av.y), tf = APPLY_TANH ? fast_tanh(bf2f(pv.y)) : bf2f(pv.y);
      o.y = f2bf(fmaxf(af + 0.1f * bf2f(bv.y) - 0.1f * (af - tf), 0.f));
    }
    {
      float af = bf2f(av.z), tf = APPLY_TANH ? fast_tanh(bf2f(pv.z)) : bf2f(pv.z);
      o.z = f2bf(fmaxf(af + 0.1f * bf2f(bv.z) - 0.1f * (af - tf), 0.f));
    }
    {
      float af = bf2f(av.w), tf = APPLY_TANH ? fast_tanh(bf2f(pv.w)) : bf2f(pv.w);
      o.w = f2bf(fmaxf(af + 0.1f * bf2f(bv.w) - 0.1f * (af - tf), 0.f));
    }
    ((ushort4*)a)[i] = o;
  }
}

__global__ void k_sig(const float* __restrict__ p, float* __restrict__ out, int n4) {
  int i = blockIdx.x * blockDim.x + threadIdx.x, st = gridDim.x * blockDim.x;
  for (; i < n4; i += st) {
    float4 v = ((const float4*)p)[i];
    float4 o;
    o.x = fast_sig(v.x); o.y = fast_sig(v.y); o.z = fast_sig(v.z); o.w = fast_sig(v.w);
    ((float4*)out)[i] = o;
  }
}

// ------------------------------------------------------------------------------------
extern "C" void kernel_launch(void* const* d_in, const int* in_sizes, int n_in,
                              void* d_out, int out_size, void* d_ws, size_t ws_size,
                              hipStream_t stream) {
  (void)in_sizes; (void)n_in; (void)out_size;
  const float* x      = (const float*)d_in[0];
  const float* target = (const float*)d_in[1];
  const float* Wf[4]  = {(const float*)d_in[2], (const float*)d_in[3],
                         (const float*)d_in[4], (const float*)d_in[5]};
  const float* We[3]  = {(const float*)d_in[6], (const float*)d_in[7], (const float*)d_in[8]};
  const size_t wN[7]  = {(size_t)4096 * 1024, (size_t)4096 * 4096, (size_t)4096 * 4096,
                         (size_t)1024 * 4096, (size_t)4096 * 4096, (size_t)4096 * 4096,
                         (size_t)4096 * 1024};
  const float* wSrc[7] = {Wf[0], Wf[1], Wf[2], Wf[3], We[0], We[1], We[2]};

  char* w = (char*)d_ws;
  size_t off = 0;
  auto alloc = [&](size_t bytes) { void* p = w + off; off += bytes; return p; };

  // ---- shared state (bf16 except p3) : ~140 MB ----
  const size_t BIG = (size_t)B_ * 4096;   // 8.4M
  const size_t SML = (size_t)B_ * 1024;   // 2.1M
  unsigned short* xb  = (unsigned short*)alloc(SML * 2);
  unsigned short* a1b = (unsigned short*)alloc(BIG * 2);
  unsigned short* a2b = (unsigned short*)alloc(BIG * 2);
  unsigned short* a3b = (unsigned short*)alloc(BIG * 2);
  unsigned short* t0b = (unsigned short*)alloc(BIG * 2);
  unsigned short* p1b = (unsigned short*)alloc(BIG * 2);
  unsigned short* p2b = (unsigned short*)alloc(BIG * 2);
  float*          p3  = (float*)alloc(SML * 4);
  unsigned short* db  = (unsigned short*)alloc(BIG * 2);
  unsigned short* btb = (unsigned short*)alloc(BIG * 2);
  const size_t rest = off;

  // weight layout: fast = all 7 pre-converted (~152 MB more); slim = 1 stage (32 MB)
  size_t wbytes = 0;
  for (int i = 0; i < 7; ++i) wbytes += wN[i] * 2;
  const bool fast = ws_size >= rest + wbytes;
  unsigned short* Wb[7];
  unsigned short* wstage = nullptr;
  if (fast) {
    for (int i = 0; i < 7; ++i) Wb[i] = (unsigned short*)alloc(wN[i] * 2);
  } else {
    wstage = (unsigned short*)alloc((size_t)4096 * 4096 * 2);
  }

  const int T = 256;
  auto blocks = [&](int n4) { int b = (n4 + T - 1) / T; return b > 2048 ? 2048 : b; };
  auto cvt = [&](const float* s, unsigned short* d, size_t n) {
    int n4 = (int)(n >> 2);
    k_cvt<<<blocks(n4), T, 0, stream>>>(s, d, n4);
  };
  // returns bf16 pointer for weight idx (converting into stage if slim)
  auto getW = [&](int idx) -> const unsigned short* {
    if (fast) return Wb[idx];
    cvt(wSrc[idx], wstage, wN[idx]);
    return wstage;
  };
  auto gemm_bf = [&](const unsigned short* A, const unsigned short* Wt, unsigned short* C,
                     int M, int N, int K) {
    dim3 g(N >> 7, M >> 7);
    gemm_bt<unsigned short><<<g, 256, 0, stream>>>(A, Wt, C, M, N, K);
  };
  auto gemm_f32 = [&](const unsigned short* A, const unsigned short* Wt, float* C,
                      int M, int N, int K) {
    dim3 g(N >> 7, M >> 7);
    gemm_bt<float><<<g, 256, 0, stream>>>(A, Wt, C, M, N, K);
  };

  const int n4_big = (int)(BIG >> 2);
  const int n4_sml = (int)(SML >> 2);

  if (fast)
    for (int i = 0; i < 7; ++i) cvt(wSrc[i], Wb[i], wN[i]);
  cvt(x, xb, SML);

  // ---- initial feedforward ----
  gemm_bf(xb, getW(0), db /*p0 tmp*/, B_, 4096, 1024);
  k_tanh_relu<<<blocks(n4_big), T, 0, stream>>>(db, t0b, a1b, n4_big);
  gemm_bf(a1b, getW(1), p1b, B_, 4096, 4096);
  k_act<<<blocks(n4_big), T, 0, stream>>>(p1b, a2b, n4_big);
  gemm_bf(a2b, getW(2), p2b, B_, 4096, 4096);
  k_act<<<blocks(n4_big), T, 0, stream>>>(p2b, a3b, n4_big);
  gemm_f32(a3b, getW(3), p3, B_, 1024, 4096);
  // a[4] = target (implicit)

  // ---- 5 inference iterations ----
  for (int it = 0; it < 5; ++it) {
    // l=1: delta1 from (p1,a2); botm = delta1 @ We0^T; a1 += (uses t0 = tanh(p0))
    k_delta_tanh<<<blocks(n4_big), T, 0, stream>>>(p1b, a2b, db, n4_big);
    gemm_bf(db, getW(4), btb, B_, 4096, 4096);
    k_update<false><<<blocks(n4_big), T, 0, stream>>>(a1b, btb, t0b, n4_big);
    // l=2: delta2 from (p2,a3); botm = delta2 @ We1^T; a2 += (uses old p1)
    k_delta_tanh<<<blocks(n4_big), T, 0, stream>>>(p2b, a3b, db, n4_big);
    gemm_bf(db, getW(5), btb, B_, 4096, 4096);
    k_update<true><<<blocks(n4_big), T, 0, stream>>>(a2b, btb, p1b, n4_big);
    // l=3: delta3 from (p3,target); botm = delta3 @ We2^T; a3 += (uses old p2)
    k_delta_sig<<<blocks(n4_sml), T, 0, stream>>>(p3, target, db, n4_sml);
    gemm_bf(db, getW(6), btb, B_, 4096, 1024);
    k_update<true><<<blocks(n4_big), T, 0, stream>>>(a3b, btb, p2b, n4_big);
    // p recompute (p0 constant)
    gemm_bf(a1b, getW(1), p1b, B_, 4096, 4096);
    gemm_bf(a2b, getW(2), p2b, B_, 4096, 4096);
    gemm_f32(a3b, getW(3), p3, B_, 1024, 4096);
  }

  // ---- output: sigmoid(p3) ----
  k_sig<<<blocks(n4_sml), T, 0, stream>>>(p3, (float*)d_out, n4_sml);
}